// Round 10
// baseline (57.106 us; speedup 1.0000x reference)
//
#include <hip/hip_runtime.h>
#include <math.h>

#define K 112
#define W 7                // workgroups; WG w owns global rows [16w, 16w+16)
#define OWNR 16
#define EXTR 64            // 24 ghost + 16 owned + 24 ghost
#define NT 256             // 16x16 tiles of 4x7 = 4 waves
#define TR 4
#define TC 7
#define NRT 16             // row tiles (64/4)
#define NCT 16             // col tiles (112/7)
#define NSTEN 23           // stencil applications after init (ghost depth 24 covers it)
#define LDPX 116           // x staging stride (16B aligned)
#define LDP 113            // d-buffer stride: lane col-stride 7 words, gcd(7,32)=1 -> bank-clean
#define MU0A 0.1f

__device__ __forceinline__ float wrapf(float v) {
    float w = fmodf(v + 1.0f, 2.0f);
    if (w < 0.0f) w += 2.0f;
    return w - 1.0f;
}
__device__ __forceinline__ float dcoef(int i) {
    // diag of L = D^T D : [1, 2, ..., 2, 3, 2]
    return (i == 0) ? 1.0f : ((i == K - 2) ? 3.0f : 2.0f);
}
__device__ __forceinline__ float ecoef(int i) {
    // off-diag e[i] connecting (i, i+1): [-1, ..., -1, -2]
    return (i == K - 2) ? -2.0f : -1.0f;
}

__global__ __launch_bounds__(NT, 1)
void robust2d_cheb7(const float* __restrict__ x_in,
                    const float* __restrict__ mu_in,
                    float* __restrict__ out) {
    __shared__ __align__(16) float xs[66 * LDPX];   // 30,624 B
    __shared__ float dbufA[EXTR * LDP];             // 28,928 B
    __shared__ float dbufB[EXTR * LDP];             // 28,928 B -> 88,480 B total

    const int wg    = blockIdx.x;
    const int ebase = OWNR * wg - 24;   // ext row e <-> global row g = ebase + e
    const int tid = threadIdx.x;
    const int ri  = tid >> 4;           // 0..15 row tile
    const int ci  = tid & 15;           // 0..15 col tile
    const int e0  = TR * ri;            // ext rows e0..e0+3
    const int j0  = TC * ci;
    const float mu = mu_in[0];

    // ---- stage x rows [ebase-1, ebase+65), clamped to [0,111] (float4) ----
    for (int e = tid; e < 66 * 28; e += NT) {
        int row = e / 28, q = (e % 28) * 4;
        int g = ebase - 1 + row;
        g = min(max(g, 0), K - 1);
        *(float4*)&xs[row * LDPX + q] = *(const float4*)(x_in + g * K + q);
    }
    __syncthreads();

#define XSG(g, j) xs[((g) - ebase + 1) * LDPX + (j)]

    // ---- RHS b on alive ext rows; dead rows (outside domain) stay exactly 0 ----
    float rr[TR][TC], dd[TR][TC], xa[TR][TC];
    float cdg[TR][TC], cvu[TR], cvd[TR], chl[TC], chr[TC];

    // column coefficients (same-row neighbors of dead rows are 0, so these are safe)
    #pragma unroll
    for (int c = 0; c < TC; ++c) {
        const int j = j0 + c;
        chl[c] = (j > 0)     ? ecoef(j - 1) : 0.0f;
        chr[c] = (j < K - 1) ? ecoef(j)     : 0.0f;
    }

    // ---- Chebyshev setup: lambda(A) in [0.1, 10.1]
    //      (Gershgorin on D D^T: tridiag(-1,2,-1) + dup-row corner -> lmax(L) <= 5) ----
    const float theta = 5.1f, delta = 5.0f;
    const float sg = theta / delta;
    float rho = 1.0f / sg;

    #pragma unroll
    for (int r = 0; r < TR; ++r) {
        const int g = ebase + e0 + r;
        const bool alive = (g >= 0) && (g < K);
        cvu[r] = (alive && g > 0)     ? ecoef(g - 1) : 0.0f;
        cvd[r] = (alive && g < K - 1) ? ecoef(g)     : 0.0f;
        #pragma unroll
        for (int c = 0; c < TC; ++c) {
            const int j = j0 + c;
            float b = 0.0f;
            if (alive) {
                float vert, horz;
                if (g == 0) {
                    vert = -wrapf(XSG(1, j) - XSG(0, j));
                } else if (g < K - 2) {
                    vert = wrapf(XSG(g, j) - XSG(g - 1, j)) - wrapf(XSG(g + 1, j) - XSG(g, j));
                } else if (g == K - 2) {
                    vert = wrapf(XSG(K - 2, j) - XSG(K - 3, j)) - 2.0f * wrapf(XSG(K - 1, j) - XSG(K - 2, j));
                } else {
                    vert = 2.0f * wrapf(XSG(K - 1, j) - XSG(K - 2, j));
                }
                if (j == 0) {
                    horz = -wrapf(XSG(g, 1) - XSG(g, 0));
                } else if (j < K - 2) {
                    horz = wrapf(XSG(g, j) - XSG(g, j - 1)) - wrapf(XSG(g, j + 1) - XSG(g, j));
                } else if (j == K - 2) {
                    horz = wrapf(XSG(g, K - 2) - XSG(g, K - 3)) - 2.0f * wrapf(XSG(g, K - 1) - XSG(g, K - 2));
                } else {
                    horz = 2.0f * wrapf(XSG(g, K - 1) - XSG(g, K - 2));
                }
                b = vert + horz + mu * XSG(g, j);
            }
            rr[r][c]  = b;
            dd[r][c]  = b * (1.0f / theta);
            xa[r][c]  = dd[r][c];
            cdg[r][c] = alive ? (dcoef(g) + dcoef(j) + MU0A) : 0.0f;
        }
    }

    // clamped halo addresses in ext space (clamped reads hit garbage-by-design rows,
    // covered by the validity model; domain edges are coef-masked)
    const int eu = (e0 > 0)         ? (e0 - 1)  : 0;
    const int ed = (e0 + TR < EXTR) ? (e0 + TR) : (EXTR - 1);
    const int jl = (j0 > 0)         ? (j0 - 1)  : 0;
    const int jr = (j0 + TC < K)    ? (j0 + TC) : (K - 1);

    // publish d0 (full tile, once)
    float* cur = dbufA;
    float* nxt = dbufB;
    #pragma unroll
    for (int r = 0; r < TR; ++r)
        #pragma unroll
        for (int c = 0; c < TC; ++c)
            cur[(e0 + r) * LDP + j0 + c] = dd[r][c];
    __syncthreads();

    // ---- 23 stencil applications, zero inter-WG syncs, 1 barrier/iter ----
    for (int it = 0; it < NSTEN; ++it) {
        float up[TC], dn[TC], lf[TR], rt[TR];
        #pragma unroll
        for (int c = 0; c < TC; ++c) up[c] = cur[eu * LDP + j0 + c];
        #pragma unroll
        for (int c = 0; c < TC; ++c) dn[c] = cur[ed * LDP + j0 + c];
        #pragma unroll
        for (int r = 0; r < TR; ++r) lf[r] = cur[(e0 + r) * LDP + jl];
        #pragma unroll
        for (int r = 0; r < TR; ++r) rt[r] = cur[(e0 + r) * LDP + jr];

        const float rho_n = 1.0f / (2.0f * sg - rho);
        const float ak = rho_n * rho;
        const float bk = 2.0f * rho_n / delta;
        rho = rho_n;

        float ap[TR][TC];
        #pragma unroll
        for (int r = 0; r < TR; ++r) {
            #pragma unroll
            for (int c = 0; c < TC; ++c) {
                float a = cdg[r][c] * dd[r][c];
                a += cvu[r] * ((r == 0)      ? up[c] : dd[r - 1][c]);
                a += cvd[r] * ((r == TR - 1) ? dn[c] : dd[r + 1][c]);
                a += chl[c] * ((c == 0)      ? lf[r] : dd[r][c - 1]);
                a += chr[c] * ((c == TC - 1) ? rt[r] : dd[r][c + 1]);
                ap[r][c] = a;
            }
        }
        #pragma unroll
        for (int r = 0; r < TR; ++r) {
            #pragma unroll
            for (int c = 0; c < TC; ++c) {
                const float rv = rr[r][c] - ap[r][c];
                rr[r][c] = rv;
                const float dv = ak * dd[r][c] + bk * rv;
                dd[r][c] = dv;
                xa[r][c] += dv;
            }
        }

        if (it != NSTEN - 1) {
            // boundary-only publish: rows 0,3 full; rows 1,2 end-cols only (18 writes)
            #pragma unroll
            for (int c = 0; c < TC; ++c) nxt[e0 * LDP + j0 + c]            = dd[0][c];
            #pragma unroll
            for (int c = 0; c < TC; ++c) nxt[(e0 + TR - 1) * LDP + j0 + c] = dd[TR - 1][c];
            #pragma unroll
            for (int r = 1; r < TR - 1; ++r) {
                nxt[(e0 + r) * LDP + j0]          = dd[r][0];
                nxt[(e0 + r) * LDP + j0 + TC - 1] = dd[r][TC - 1];
            }
            __syncthreads();
            float* t = cur; cur = nxt; nxt = t;
        }
    }

    // ---- write owned rows (ext rows 24..39 = row tiles 6..9) ----
    if (ri >= 6 && ri < 10) {
        #pragma unroll
        for (int r = 0; r < TR; ++r) {
            const int g = ebase + e0 + r;
            #pragma unroll
            for (int c = 0; c < TC; ++c)
                out[g * K + j0 + c] = xa[r][c];
        }
    }
}

extern "C" void kernel_launch(void* const* d_in, const int* in_sizes, int n_in,
                              void* d_out, int out_size, void* d_ws, size_t ws_size,
                              hipStream_t stream) {
    const float* x  = (const float*)d_in[0];
    const float* mu = (const float*)d_in[1];
    // d_in[2]=A, d_in[3]=DM, d_in[4]=DN: structure exploited analytically, unused
    float* out = (float*)d_out;
    robust2d_cheb7<<<W, NT, 0, stream>>>(x, mu, out);
}

// Round 11
// 50.056 us; speedup vs baseline: 1.1408x; 1.1408x over previous
//
#include <hip/hip_runtime.h>
#include <math.h>

#define K 112
#define NT 512             // 8 waves per WG (2/SIMD: latency-hidden regime)
#define TR 2
#define TC 8
#define NRT 34             // 68 ext rows / 2
#define NCT 14             // 112 / 8
#define NACT (NRT * NCT)   // 476 active threads
#define EXTR 68            // WG0: rows 0..67, WG1: rows 44..111 (12-row ghost overlap each)
#define PH0 12             // phase-0 iterations (= ghost depth)
#define PH1 10             // phase-1 iterations (<= ghost depth)
#define LDP 116            // d-buffer stride: multiple of 4 -> 16B-aligned float4 tiles
#define LDPX 116
#define MU0A 0.1f

__device__ __forceinline__ float wrapf(float v) {
    float w = fmodf(v + 1.0f, 2.0f);
    if (w < 0.0f) w += 2.0f;
    return w - 1.0f;
}
__device__ __forceinline__ float dcoef(int i) {
    // diag of L = D^T D : [1, 2, ..., 2, 3, 2]
    return (i == 0) ? 1.0f : ((i == K - 2) ? 3.0f : 2.0f);
}
__device__ __forceinline__ float ecoef(int i) {
    // off-diag e[i] connecting (i, i+1): [-1, ..., -1, -2]
    return (i == K - 2) ? -2.0f : -1.0f;
}

__global__ __launch_bounds__(NT, 1)
void robust2d_cheb2(const float* __restrict__ x_in,
                    const float* __restrict__ mu_in,
                    float* __restrict__ out,
                    float* __restrict__ ws) {
    __shared__ __align__(16) float xs[70 * LDPX];   // 32,480 B
    __shared__ __align__(16) float dbufA[EXTR * LDP];  // 31,552 B
    __shared__ __align__(16) float dbufB[EXTR * LDP];  // 31,552 B -> 95,584 B total

    const int wg    = blockIdx.x;            // 0: ext rows 0..67; 1: ext rows 44..111
    const int ebase = wg ? 44 : 0;
    const int tid = threadIdx.x;
    const int ri  = tid / NCT;               // row tile (active < 34)
    const int ci  = tid - ri * NCT;          // col tile 0..13
    const bool act = (ri < NRT);
    const int e0  = act ? (TR * ri) : 0;     // ext rows e0, e0+1
    const int g0  = ebase + e0;              // global rows (always in [0,111])
    const int j0  = TC * ci;
    const float mu = mu_in[0];

    // ws: flags at word 0 (wg0) / word 32 (wg1); exchange region from word 64:
    // xdd[24][112] for global rows 44..67, then xrr[24][112]
    int*   flags = (int*)ws;
    float* xdd   = ws + 64;
    float* xrr   = xdd + 24 * K;

    // ---- stage x rows [ebase-1, ebase+69), clamped to [0,111] (float4) ----
    for (int e = tid; e < 70 * 28; e += NT) {
        int row = e / 28, q = (e % 28) * 4;
        int g = ebase - 1 + row;
        g = min(max(g, 0), K - 1);
        *(float4*)&xs[row * LDPX + q] = *(const float4*)(x_in + g * K + q);
    }
    __syncthreads();

#define XSG(g, j) xs[((g) - ebase + 1) * LDPX + (j)]

    // ---- Chebyshev setup: lambda(A) in [0.1, 10.1] (Gershgorin on D D^T, r10-validated) ----
    const float theta = 5.1f, delta = 5.0f;
    const float sg = theta / delta;
    float rho = 1.0f / sg;

    // ---- RHS + init on ext rows (all in-domain for both WGs) ----
    float rr[TR][TC], dd[TR][TC], xa[TR][TC];
    float cdg[TR][TC], cvu[TR], cvd[TR], chl[TC], chr[TC];
    #pragma unroll
    for (int c = 0; c < TC; ++c) {
        const int j = j0 + c;
        chl[c] = (j > 0)     ? ecoef(j - 1) : 0.0f;
        chr[c] = (j < K - 1) ? ecoef(j)     : 0.0f;
    }
    #pragma unroll
    for (int r = 0; r < TR; ++r) {
        const int g = g0 + r;
        cvu[r] = (g > 0)     ? ecoef(g - 1) : 0.0f;
        cvd[r] = (g < K - 1) ? ecoef(g)     : 0.0f;
        #pragma unroll
        for (int c = 0; c < TC; ++c) {
            const int j = j0 + c;
            float b = 0.0f;
            if (act) {
                float vert, horz;
                if (g == 0) {
                    vert = -wrapf(XSG(1, j) - XSG(0, j));
                } else if (g < K - 2) {
                    vert = wrapf(XSG(g, j) - XSG(g - 1, j)) - wrapf(XSG(g + 1, j) - XSG(g, j));
                } else if (g == K - 2) {
                    vert = wrapf(XSG(K - 2, j) - XSG(K - 3, j)) - 2.0f * wrapf(XSG(K - 1, j) - XSG(K - 2, j));
                } else {
                    vert = 2.0f * wrapf(XSG(K - 1, j) - XSG(K - 2, j));
                }
                if (j == 0) {
                    horz = -wrapf(XSG(g, 1) - XSG(g, 0));
                } else if (j < K - 2) {
                    horz = wrapf(XSG(g, j) - XSG(g, j - 1)) - wrapf(XSG(g, j + 1) - XSG(g, j));
                } else if (j == K - 2) {
                    horz = wrapf(XSG(g, K - 2) - XSG(g, K - 3)) - 2.0f * wrapf(XSG(g, K - 1) - XSG(g, K - 2));
                } else {
                    horz = 2.0f * wrapf(XSG(g, K - 1) - XSG(g, K - 2));
                }
                b = vert + horz + mu * XSG(g, j);
            }
            rr[r][c]  = b;
            dd[r][c]  = b * (1.0f / theta);
            xa[r][c]  = dd[r][c];
            cdg[r][c] = dcoef(g) + dcoef(j) + MU0A;
        }
    }

    // halo addresses (ext-edge clamps hit garbage-by-design rows: validity-model-covered;
    // domain edges are coef-masked)
    const int eu = (e0 > 0)         ? (e0 - 1) : 0;
    const int ed = (e0 + 2 < EXTR)  ? (e0 + 2) : (EXTR - 1);
    const int jl = (j0 > 0)         ? (j0 - 1) : 0;
    const int jr = (j0 + TC < K)    ? (j0 + TC) : (K - 1);

    // publish d0 (float4 x4)
    float* cur = dbufA;
    float* nxt = dbufB;
    if (act) {
        *(float4*)&cur[e0 * LDP + j0]           = *(float4*)&dd[0][0];
        *(float4*)&cur[e0 * LDP + j0 + 4]       = *(float4*)&dd[0][4];
        *(float4*)&cur[(e0 + 1) * LDP + j0]     = *(float4*)&dd[1][0];
        *(float4*)&cur[(e0 + 1) * LDP + j0 + 4] = *(float4*)&dd[1][4];
    }
    __syncthreads();

    // ---- 2 phases (12 + 10 iters), ONE inter-WG sync ----
    for (int ph = 0; ph < 2; ++ph) {
        const int nit = ph ? PH1 : PH0;
        for (int s = 0; s < nit; ++s) {
            const bool last = (ph == 1) && (s == nit - 1);
            const float rho_n = 1.0f / (2.0f * sg - rho);
            const float ak = rho_n * rho;
            const float bk = 2.0f * rho_n / delta;
            rho = rho_n;

            if (act) {
                float up[TC], dn[TC], lf[TR], rt[TR];
                *(float4*)&up[0] = *(const float4*)&cur[eu * LDP + j0];
                *(float4*)&up[4] = *(const float4*)&cur[eu * LDP + j0 + 4];
                *(float4*)&dn[0] = *(const float4*)&cur[ed * LDP + j0];
                *(float4*)&dn[4] = *(const float4*)&cur[ed * LDP + j0 + 4];
                lf[0] = cur[e0 * LDP + jl];       lf[1] = cur[(e0 + 1) * LDP + jl];
                rt[0] = cur[e0 * LDP + jr];       rt[1] = cur[(e0 + 1) * LDP + jr];

                float ap[TR][TC];
                #pragma unroll
                for (int r = 0; r < TR; ++r) {
                    #pragma unroll
                    for (int c = 0; c < TC; ++c) {
                        float a = cdg[r][c] * dd[r][c];
                        a += cvu[r] * ((r == 0) ? up[c] : dd[0][c]);
                        a += cvd[r] * ((r == 1) ? dn[c] : dd[1][c]);
                        a += chl[c] * ((c == 0)      ? lf[r] : dd[r][c - 1]);
                        a += chr[c] * ((c == TC - 1) ? rt[r] : dd[r][c + 1]);
                        ap[r][c] = a;
                    }
                }
                #pragma unroll
                for (int r = 0; r < TR; ++r) {
                    #pragma unroll
                    for (int c = 0; c < TC; ++c) {
                        const float rv = rr[r][c] - ap[r][c];
                        rr[r][c] = rv;
                        const float dv = ak * dd[r][c] + bk * rv;
                        dd[r][c] = dv;
                        xa[r][c] += dv;
                    }
                }
            }

            if (!last) {
                if (act) {
                    *(float4*)&nxt[e0 * LDP + j0]           = *(float4*)&dd[0][0];
                    *(float4*)&nxt[e0 * LDP + j0 + 4]       = *(float4*)&dd[0][4];
                    *(float4*)&nxt[(e0 + 1) * LDP + j0]     = *(float4*)&dd[1][0];
                    *(float4*)&nxt[(e0 + 1) * LDP + j0 + 4] = *(float4*)&dd[1][4];
                }
                __syncthreads();
                float* t = cur; cur = nxt; nxt = t;
            }
        }

        if (ph == 0) {
            // publish owned boundary rows to global (device-scope atomics land at the
            // coherence point): WG0 -> global rows 44..55 (ri 22..27),
            //                   WG1 -> global rows 56..67 (ri 6..11)
            const bool pub = act && (wg == 0 ? (ri >= 22 && ri < 28) : (ri >= 6 && ri < 12));
            if (pub) {
                #pragma unroll
                for (int r = 0; r < TR; ++r) {
                    const int slot = (g0 + r) - 44;
                    #pragma unroll
                    for (int c = 0; c < TC; ++c) {
                        atomicExch(&xdd[slot * K + j0 + c], dd[r][c]);
                        atomicExch(&xrr[slot * K + j0 + c], rr[r][c]);
                    }
                }
            }
            __syncthreads();
            if (tid == 0) {
                __threadfence();
                atomicAdd(&flags[wg * 32], 1);
                while (atomicAdd(&flags[(1 - wg) * 32], 0) < 1) { }
            }
            __syncthreads();
            // refresh ghost rows: WG0 <- rows 56..67 (ri 28..33), WG1 <- rows 44..55 (ri 0..5)
            const bool gh = act && (wg == 0 ? (ri >= 28) : (ri < 6));
            if (gh) {
                #pragma unroll
                for (int r = 0; r < TR; ++r) {
                    const int slot = (g0 + r) - 44;
                    #pragma unroll
                    for (int c = 0; c < TC; ++c) {
                        const float dv = xdd[slot * K + j0 + c];
                        const float rv = xrr[slot * K + j0 + c];
                        dd[r][c] = dv;
                        rr[r][c] = rv;
                        cur[(e0 + r) * LDP + j0 + c] = dv;
                    }
                }
            }
            __syncthreads();
        }
    }

    // ---- write owned rows: WG0 rows 0..55 (ri<28), WG1 rows 56..111 (ri>=6) ----
    const bool own = act && (wg == 0 ? (ri < 28) : (ri >= 6));
    if (own) {
        #pragma unroll
        for (int r = 0; r < TR; ++r) {
            *(float4*)(out + (g0 + r) * K + j0)     = *(float4*)&xa[r][0];
            *(float4*)(out + (g0 + r) * K + j0 + 4) = *(float4*)&xa[r][4];
        }
    }
}

extern "C" void kernel_launch(void* const* d_in, const int* in_sizes, int n_in,
                              void* d_out, int out_size, void* d_ws, size_t ws_size,
                              hipStream_t stream) {
    const float* x  = (const float*)d_in[0];
    const float* mu = (const float*)d_in[1];
    // d_in[2]=A, d_in[3]=DM, d_in[4]=DN: structure exploited analytically, unused
    float* out = (float*)d_out;
    float* ws  = (float*)d_ws;      // flags (256 B) + exchange dd/rr (21 KB)
    hipMemsetAsync(d_ws, 0, 256, stream);   // zero sync flags every replay (capture-legal)
    robust2d_cheb2<<<2, NT, 0, stream>>>(x, mu, out, ws);
}

// Round 12
// 28.588 us; speedup vs baseline: 1.9976x; 1.7510x over previous
//
#include <hip/hip_runtime.h>
#include <math.h>

#define K 112
#define W 8                // workgroups; WG w owns global rows [14w, 14w+14)
#define OWN 14
#define GH 22              // ghost depth each side = stencil count (validity decays 1/iter)
#define EXTR 58            // 22 + 14 + 22
#define NSTEN 22           // stencils after init -> total degree 23 (r11-validated accuracy)
#define NT 512             // 29x16 tiles of 2x7 = 464 active; ~1.9 waves/SIMD
#define TR 2
#define TC 7
#define NRT 29             // ceil? 58/2 = 29 row tiles
#define NCT 16
#define LDPX 116           // x staging stride (16B aligned)
#define LDP 113            // d-buffer stride: lane col-stride 7 words, gcd(7,32)=1 -> bank-clean
#define MU0A 0.1f

// wrap(v) = ((v+1) mod 2) - 1 with Python mod semantics = v - 2*floor(v/2 + 1/2).
// 3 VALU ops (fma, floor, fma) instead of fmodf's ~20.
__device__ __forceinline__ float wrapf(float v) {
    return v - 2.0f * floorf(0.5f * v + 0.5f);
}
__device__ __forceinline__ float dcoef(int i) {
    // diag of L = D^T D : [1, 2, ..., 2, 3, 2]
    return (i == 0) ? 1.0f : ((i == K - 2) ? 3.0f : 2.0f);
}
__device__ __forceinline__ float ecoef(int i) {
    // off-diag e[i] connecting (i, i+1): [-1, ..., -1, -2]
    return (i == K - 2) ? -2.0f : -1.0f;
}

__global__ __launch_bounds__(NT, 1)
void robust2d_cheb8(const float* __restrict__ x_in,
                    const float* __restrict__ mu_in,
                    float* __restrict__ out) {
    __shared__ __align__(16) float xs[60 * LDPX];      // 27,840 B
    __shared__ float dbufA[EXTR * LDP];                // 26,216 B
    __shared__ float dbufB[EXTR * LDP];                // 26,216 B -> 80,272 B (>80KB: 1 WG/CU)

    const int wg    = blockIdx.x;
    const int ebase = OWN * wg - GH;    // ext row e <-> global row g = ebase + e
    const int tid = threadIdx.x;
    const int ri  = tid >> 4;           // 0..31 (active < 29)
    const int ci  = tid & 15;           // 0..15
    const bool act = (ri < NRT);
    const int e0  = act ? (TR * ri) : 0;
    const int j0  = TC * ci;
    const float mu = mu_in[0];

    // ---- stage x rows [ebase-1, ebase+59), clamped to [0,111] (float4) ----
    for (int e = tid; e < 60 * 28; e += NT) {
        int row = e / 28, q = (e % 28) * 4;
        int g = ebase - 1 + row;
        g = min(max(g, 0), K - 1);
        *(float4*)&xs[row * LDPX + q] = *(const float4*)(x_in + g * K + q);
    }
    __syncthreads();

#define XSG(g, j) xs[((g) - ebase + 1) * LDPX + (j)]

    // ---- Chebyshev setup: lambda(A) in [0.1, 10.1] (Gershgorin on D D^T, r10-validated) ----
    const float theta = 5.1f, delta = 5.0f;
    const float sg = theta / delta;
    float rho = 1.0f / sg;

    // ---- RHS + init on ext rows; dead rows (outside domain) stay exactly 0 ----
    float rr[TR][TC], dd[TR][TC], xa[TR][TC];
    float cdg[TR][TC], cvu[TR], cvd[TR], chl[TC], chr[TC];
    #pragma unroll
    for (int c = 0; c < TC; ++c) {
        const int j = j0 + c;
        chl[c] = (j > 0)     ? ecoef(j - 1) : 0.0f;
        chr[c] = (j < K - 1) ? ecoef(j)     : 0.0f;
    }
    #pragma unroll
    for (int r = 0; r < TR; ++r) {
        const int g = ebase + e0 + r;
        const bool alive = act && (g >= 0) && (g < K);
        cvu[r] = (alive && g > 0)     ? ecoef(g - 1) : 0.0f;
        cvd[r] = (alive && g < K - 1) ? ecoef(g)     : 0.0f;
        #pragma unroll
        for (int c = 0; c < TC; ++c) {
            const int j = j0 + c;
            float b = 0.0f;
            if (alive) {
                float vert, horz;
                if (g == 0) {
                    vert = -wrapf(XSG(1, j) - XSG(0, j));
                } else if (g < K - 2) {
                    vert = wrapf(XSG(g, j) - XSG(g - 1, j)) - wrapf(XSG(g + 1, j) - XSG(g, j));
                } else if (g == K - 2) {
                    vert = wrapf(XSG(K - 2, j) - XSG(K - 3, j)) - 2.0f * wrapf(XSG(K - 1, j) - XSG(K - 2, j));
                } else {
                    vert = 2.0f * wrapf(XSG(K - 1, j) - XSG(K - 2, j));
                }
                if (j == 0) {
                    horz = -wrapf(XSG(g, 1) - XSG(g, 0));
                } else if (j < K - 2) {
                    horz = wrapf(XSG(g, j) - XSG(g, j - 1)) - wrapf(XSG(g, j + 1) - XSG(g, j));
                } else if (j == K - 2) {
                    horz = wrapf(XSG(g, K - 2) - XSG(g, K - 3)) - 2.0f * wrapf(XSG(g, K - 1) - XSG(g, K - 2));
                } else {
                    horz = 2.0f * wrapf(XSG(g, K - 1) - XSG(g, K - 2));
                }
                b = vert + horz + mu * XSG(g, j);
            }
            rr[r][c]  = b;
            dd[r][c]  = b * (1.0f / theta);
            xa[r][c]  = dd[r][c];
            cdg[r][c] = alive ? (dcoef(g) + dcoef(j) + MU0A) : 0.0f;
        }
    }

    // halo addresses (ext-edge clamps read garbage-by-design rows, covered by the
    // validity-decay model; domain edges are coef-masked)
    const int eu = (e0 > 0)        ? (e0 - 1) : 0;
    const int ed = (e0 + 2 < EXTR) ? (e0 + 2) : (EXTR - 1);
    const int jl = (j0 > 0)        ? (j0 - 1) : 0;
    const int jr = (j0 + TC < K)   ? (j0 + TC) : (K - 1);

    // publish d0
    float* cur = dbufA;
    float* nxt = dbufB;
    if (act) {
        #pragma unroll
        for (int r = 0; r < TR; ++r)
            #pragma unroll
            for (int c = 0; c < TC; ++c)
                cur[(e0 + r) * LDP + j0 + c] = dd[r][c];
    }
    __syncthreads();

    // ---- 22 stencils, zero inter-WG syncs, 1 barrier/iter ----
    for (int it = 0; it < NSTEN; ++it) {
        const float rho_n = 1.0f / (2.0f * sg - rho);
        const float ak = rho_n * rho;
        const float bk = 2.0f * rho_n / delta;
        rho = rho_n;

        if (act) {
            float up[TC], dn[TC], lf[TR], rt[TR];
            #pragma unroll
            for (int c = 0; c < TC; ++c) up[c] = cur[eu * LDP + j0 + c];
            #pragma unroll
            for (int c = 0; c < TC; ++c) dn[c] = cur[ed * LDP + j0 + c];
            #pragma unroll
            for (int r = 0; r < TR; ++r) lf[r] = cur[(e0 + r) * LDP + jl];
            #pragma unroll
            for (int r = 0; r < TR; ++r) rt[r] = cur[(e0 + r) * LDP + jr];

            float ap[TR][TC];
            #pragma unroll
            for (int r = 0; r < TR; ++r) {
                #pragma unroll
                for (int c = 0; c < TC; ++c) {
                    float a = cdg[r][c] * dd[r][c];
                    a += cvu[r] * ((r == 0) ? up[c] : dd[0][c]);
                    a += cvd[r] * ((r == 1) ? dn[c] : dd[1][c]);
                    a += chl[c] * ((c == 0)      ? lf[r] : dd[r][c - 1]);
                    a += chr[c] * ((c == TC - 1) ? rt[r] : dd[r][c + 1]);
                    ap[r][c] = a;
                }
            }
            #pragma unroll
            for (int r = 0; r < TR; ++r) {
                #pragma unroll
                for (int c = 0; c < TC; ++c) {
                    const float rv = rr[r][c] - ap[r][c];
                    rr[r][c] = rv;
                    const float dv = ak * dd[r][c] + bk * rv;
                    dd[r][c] = dv;
                    xa[r][c] += dv;
                }
            }
        }

        if (it != NSTEN - 1) {
            if (act) {
                #pragma unroll
                for (int r = 0; r < TR; ++r)
                    #pragma unroll
                    for (int c = 0; c < TC; ++c)
                        nxt[(e0 + r) * LDP + j0 + c] = dd[r][c];
            }
            __syncthreads();
            float* t = cur; cur = nxt; nxt = t;
        }
    }

    // ---- write owned rows: ext rows [22,36) = row tiles 11..17 -> global [14wg, 14wg+14) ----
    if (act && ri >= 11 && ri < 18) {
        #pragma unroll
        for (int r = 0; r < TR; ++r) {
            const int g = ebase + e0 + r;
            #pragma unroll
            for (int c = 0; c < TC; ++c)
                out[g * K + j0 + c] = xa[r][c];
        }
    }
}

extern "C" void kernel_launch(void* const* d_in, const int* in_sizes, int n_in,
                              void* d_out, int out_size, void* d_ws, size_t ws_size,
                              hipStream_t stream) {
    const float* x  = (const float*)d_in[0];
    const float* mu = (const float*)d_in[1];
    // d_in[2]=A, d_in[3]=DM, d_in[4]=DN: structure exploited analytically, unused
    float* out = (float*)d_out;
    robust2d_cheb8<<<W, NT, 0, stream>>>(x, mu, out);
}